// Round 5
// baseline (104.363 us; speedup 1.0000x reference)
//
#include <hip/hip_runtime.h>
#include <math.h>

#define MAXB 1024   // max segments staged in LDS
#define NBLK 2048   // 8 blocks/CU * 256 CU

// ---- fallback setup (B > 64): starts[B+1] prefix + inverse softmax denom ----
__global__ void esl_setup(const int* __restrict__ lengths, int B,
                          const float* __restrict__ gamma_p,
                          int* __restrict__ starts,
                          float* __restrict__ inv_ssum) {
    const int tid = threadIdx.x;
    if (tid == 0) {
        int acc = 0;
        starts[0] = 0;
        for (int b = 0; b < B; ++b) { acc += lengths[b]; starts[b + 1] = acc; }
    }
    const float g = gamma_p[0];
    for (int b = tid; b < B; b += blockDim.x) {
        const int L = lengths[b];
        if (L <= 0) { inv_ssum[b] = 0.f; continue; }
        const int dni = (L - 1) > 1 ? (L - 1) : 1;
        const float a = 2.f * g / (float)dni;
        float ss;
        if (fabsf(a) < 1e-20f) ss = (float)L * __expf(-2.f * g);
        else ss = __expf(-2.f * g) * (expm1f(a * (float)L) / expm1f(a));
        inv_ssum[b] = 1.f / ss;
    }
}

__device__ __forceinline__ float sumexp16(const float4 v0, const float4 v1,
                                          const float4 v2, const float4 v3) {
    return __expf(v0.x) + __expf(v0.y) + __expf(v0.z) + __expf(v0.w)
         + __expf(v1.x) + __expf(v1.y) + __expf(v1.z) + __expf(v1.w)
         + __expf(v2.x) + __expf(v2.y) + __expf(v2.z) + __expf(v2.w)
         + __expf(v3.x) + __expf(v3.y) + __expf(v3.z) + __expf(v3.w);
}

// ---- main: contiguous chunk per wave, pair compute, 1-pair-ahead pipeline ----
__global__ __launch_bounds__(256)
void esl_main(const float* __restrict__ outputs,
              const int* __restrict__ targets,
              const int* __restrict__ lengths,
              const int* __restrict__ g_starts,
              const float* __restrict__ g_inv,
              const float* __restrict__ gamma_p,
              int T, int B, int C, int inblock,
              float* __restrict__ partials) {
    __shared__ int   sh_starts[MAXB + 1];
    __shared__ float sh_inv[MAXB];
    __shared__ float sh_part[4];

    const int tid = threadIdx.x;
    const float g = gamma_p[0];

    if (inblock) {
        // B <= 64: wave 0 builds starts + inv_ssum locally (shfl prefix scan)
        if (tid < 64) {
            const int b = tid;
            const int len = (b < B) ? lengths[b] : 0;
            int sc = len;
            #pragma unroll
            for (int off = 1; off < 64; off <<= 1) {
                const int u = __shfl_up(sc, off, 64);
                if (tid >= off) sc += u;
            }
            if (b < B) {
                sh_starts[b] = sc - len;
                if (b == B - 1) sh_starts[B] = sc;
                float inv = 0.f;
                const int L = len;
                if (L > 0) {
                    const int dni = (L - 1) > 1 ? (L - 1) : 1;
                    const float a = 2.f * g / (float)dni;
                    float ss;
                    if (fabsf(a) < 1e-20f) ss = (float)L * __expf(-2.f * g);
                    else ss = __expf(-2.f * g) * (expm1f(a * (float)L) / expm1f(a));
                    inv = 1.f / ss;
                }
                sh_inv[b] = inv;
            }
        }
    } else {
        const int nb = (B < MAXB) ? B : MAXB;
        for (int i = tid; i < nb + 1; i += blockDim.x) sh_starts[i] = g_starts[i];
        for (int i = tid; i < nb;     i += blockDim.x) sh_inv[i]   = g_inv[i];
    }
    __syncthreads();

    const int wid  = tid >> 6;
    const int lane = tid & 63;
    const int* stp    = (B <= MAXB) ? sh_starts : g_starts;
    const float* invp = (B <= MAXB) ? sh_inv    : g_inv;

    float acc = 0.f;

    if (C == 1024) {
        const int nwaves = gridDim.x * 4;
        const int w = blockIdx.x * 4 + wid;
        const int npw = (T + nwaves - 1) / nwaves;
        const int tbeg = w * npw;
        const int tend = (tbeg + npw < T) ? tbeg + npw : T;

        if (tbeg < T) {
            // wave's targets cached in a lane register (npw <= 64 fast case)
            const int use_shfl = (npw <= 64);
            int tg = 0;
            if (use_shfl) {
                int ti = tbeg + lane;
                if (ti > T - 1) ti = T - 1;
                tg = targets[ti];
            }

            // one binary search per wave; segment state lives in registers
            int lo = 0, hi = B - 1;
            while (lo < hi) {
                const int mid = (lo + hi + 1) >> 1;
                if (stp[mid] <= tbeg) lo = mid; else hi = mid - 1;
            }
            int seg = lo;
            int st  = stp[seg];
            int en  = stp[seg + 1];
            float slope, winv;
            {
                const float dnl = fmaxf((float)(en - st) - 1.f, 1.f);
                slope = __fdividef(2.f * g, dnl);
                winv  = invp[seg];
            }
            const float n2g = -2.f * g;

            #define ESL_ADV(tt)                                                    \
                while ((tt) >= en && seg + 1 < B) {                                \
                    ++seg; st = en; en = stp[seg + 1];                             \
                    const float dnl_ = fmaxf((float)(en - st) - 1.f, 1.f);         \
                    slope = __fdividef(2.f * g, dnl_);                             \
                    winv  = invp[seg];                                             \
                }

            // load pair (tt, min(tt+1,tend-1)) rows + target logits
            #define LOADPAIR(V00,V01,V02,V03, V10,V11,V12,V13, X0, X1, tt)         \
                do {                                                               \
                    const int _t0 = (tt);                                          \
                    const int _t1 = ((tt) + 1 < tend) ? (tt) + 1 : (tt);           \
                    const float* _p0 = outputs + (size_t)_t0 * 1024;               \
                    const float* _p1 = outputs + (size_t)_t1 * 1024;               \
                    const float4* _q0 = (const float4*)_p0;                        \
                    const float4* _q1 = (const float4*)_p1;                        \
                    V00 = _q0[lane];       V01 = _q0[lane + 64];                   \
                    V02 = _q0[lane + 128]; V03 = _q0[lane + 192];                  \
                    V10 = _q1[lane];       V11 = _q1[lane + 64];                   \
                    V12 = _q1[lane + 128]; V13 = _q1[lane + 192];                  \
                    const int _c0 = use_shfl ? __shfl(tg, _t0 - tbeg, 64)          \
                                             : targets[_t0];                       \
                    const int _c1 = use_shfl ? __shfl(tg, _t1 - tbeg, 64)          \
                                             : targets[_t1];                       \
                    X0 = _p0[_c0];                                                 \
                    X1 = _p1[_c1];                                                 \
                } while (0)

            #define COMPPAIR(V00,V01,V02,V03, V10,V11,V12,V13, X0, X1, tt)         \
                do {                                                               \
                    float _sa = sumexp16(V00, V01, V02, V03);                      \
                    float _sb = sumexp16(V10, V11, V12, V13);                      \
                    _Pragma("unroll")                                              \
                    for (int _o = 32; _o; _o >>= 1) {                              \
                        _sa += __shfl_xor(_sa, _o, 64);                            \
                        _sb += __shfl_xor(_sb, _o, 64);                            \
                    }                                                              \
                    const float _lseA = __logf(_sa);                               \
                    const float _lseB = __logf(_sb);                               \
                    ESL_ADV(tt);                                                   \
                    const float _wA =                                              \
                        __expf(fmaf((float)((tt) - st), slope, n2g)) * winv;       \
                    acc += (_lseA - (X0)) * _wA;                                   \
                    if ((tt) + 1 < tend) {                                         \
                        ESL_ADV((tt) + 1);                                         \
                        const float _wB =                                          \
                            __expf(fmaf((float)((tt) + 1 - st), slope, n2g))       \
                            * winv;                                                \
                        acc += (_lseB - (X1)) * _wB;                               \
                    }                                                              \
                } while (0)

            float4 A0, A1, A2, A3, B0, B1, B2, B3;
            float4 N0, N1, N2, N3, M0, M1, M2, M3;
            float AX0, AX1, NX0, NX1;

            LOADPAIR(A0, A1, A2, A3, B0, B1, B2, B3, AX0, AX1, tbeg);
            #pragma unroll 2
            for (int t = tbeg; t < tend; t += 2) {
                const int tn = (t + 2 < tend) ? t + 2 : t;  // clamp: last iter re-load
                LOADPAIR(N0, N1, N2, N3, M0, M1, M2, M3, NX0, NX1, tn);
                COMPPAIR(A0, A1, A2, A3, B0, B1, B2, B3, AX0, AX1, t);
                A0 = N0; A1 = N1; A2 = N2; A3 = N3;
                B0 = M0; B1 = M1; B2 = M2; B3 = M3;
                AX0 = NX0; AX1 = NX1;
            }
            #undef COMPPAIR
            #undef LOADPAIR
            #undef ESL_ADV
        }
    } else {
        // generic path (max-subtracted, per-token binary search), grid-stride
        const int stride = gridDim.x * 4;
        for (int t = blockIdx.x * 4 + wid; t < T; t += stride) {
            const float* rowp = outputs + (size_t)t * (size_t)C;
            const float xt = rowp[targets[t]];
            float m = -3.402823e38f, s = 0.f;
            for (int j = lane; j < C; j += 64) m = fmaxf(m, rowp[j]);
            #pragma unroll
            for (int off = 32; off; off >>= 1) m = fmaxf(m, __shfl_xor(m, off, 64));
            for (int j = lane; j < C; j += 64) s += __expf(rowp[j] - m);
            #pragma unroll
            for (int off = 32; off; off >>= 1) s += __shfl_xor(s, off, 64);
            const float lse = m + __logf(s);
            int lo = 0, hi = B - 1;
            while (lo < hi) {
                const int mid = (lo + hi + 1) >> 1;
                if (stp[mid] <= t) lo = mid; else hi = mid - 1;
            }
            const int st  = stp[lo];
            const int L   = stp[lo + 1] - st;
            const int pos = t - st;
            const float dn  = (float)((L - 1) > 1 ? (L - 1) : 1);
            const float raw = -g + (2.f * g) * ((float)pos / dn);
            acc += (lse - xt) * __expf(raw - g) * invp[lo];
        }
    }

    if (lane == 0) sh_part[wid] = acc;
    __syncthreads();
    if (tid == 0)
        partials[blockIdx.x] = sh_part[0] + sh_part[1] + sh_part[2] + sh_part[3];
}

// ---- finish: reduce partials, divide by B ----
__global__ __launch_bounds__(256)
void esl_finish(const float* __restrict__ partials, int n, int B,
                float* __restrict__ out) {
    __shared__ float sh[4];
    float s = 0.f;
    for (int i = threadIdx.x; i < n; i += blockDim.x) s += partials[i];
    #pragma unroll
    for (int off = 32; off; off >>= 1) s += __shfl_xor(s, off, 64);
    const int wid = threadIdx.x >> 6;
    if ((threadIdx.x & 63) == 0) sh[wid] = s;
    __syncthreads();
    if (threadIdx.x == 0) out[0] = (sh[0] + sh[1] + sh[2] + sh[3]) / (float)B;
}

extern "C" void kernel_launch(void* const* d_in, const int* in_sizes, int n_in,
                              void* d_out, int out_size, void* d_ws, size_t ws_size,
                              hipStream_t stream) {
    const float* outputs = (const float*)d_in[0];
    const int*   targets = (const int*)d_in[1];
    const int*   lengths = (const int*)d_in[2];
    const float* gamma   = (const float*)d_in[3];
    float* out = (float*)d_out;

    const int T = in_sizes[1];
    const int B = in_sizes[2];
    const int C = (int)(in_sizes[0] / T);

    int*   starts   = (int*)d_ws;
    float* inv_ssum = (float*)((char*)d_ws + sizeof(int) * (size_t)(B + 1));
    float* partials = inv_ssum + B;

    const int inblock = (B <= 64) ? 1 : 0;
    if (!inblock)
        esl_setup<<<1, 256, 0, stream>>>(lengths, B, gamma, starts, inv_ssum);

    int grid = NBLK;
    const int max_needed = (T + 3) / 4;
    if (grid > max_needed) grid = max_needed;
    esl_main<<<grid, 256, 0, stream>>>(outputs, targets, lengths, starts, inv_ssum,
                                       gamma, T, B, C, inblock, partials);
    esl_finish<<<1, 256, 0, stream>>>(partials, grid, B, out);
}